// Round 1
// baseline (640.210 us; speedup 1.0000x reference)
//
#include <hip/hip_runtime.h>
#include <math.h>

// Problem dims (fixed by the reference)
#define ED 16      // EDGE_DIM
#define HD 32      // HIDDEN (== NODE_DIM == in_channels)
#define OD 32      // OUT_DIM
#define KD 1024    // HD*OD
#define OSPLIT 2   // split output channels across gridDim.y for wave balance
#define OCH (OD / OSPLIT)

// Workspace layout (floats). BN scales folded into weights.
constexpr int OFF_W1 = 0;               // W1fT [32][16]  (transposed, bn1-scaled)
constexpr int OFF_B1 = 512;             // b1f  [32]
constexpr int OFF_BF = 544;             // bf   [1024]
constexpr int OFF_W2 = 1568;            // W2fT [1024][32] (transposed, bn2-scaled), 16B-aligned
constexpr int WS_FLOATS = OFF_W2 + KD * HD;  // 34336 floats = 137344 B

// ---------------------------------------------------------------------------
// Prep: fold BN1/BN2 (eval-mode affine) into weights & biases, transpose W2.
//   h' = (ea@W1 + b1 - m1)*s1 + be1  ->  ea@W1f + b1f,  W1f[:,c] = W1[:,c]*s1[c]
//   w' = (h@W2 + b2 - m2)*s2 + be2   ->  h@W2f  + bf,   W2f[:,k] = W2[:,k]*s2[k]
// ---------------------------------------------------------------------------
__global__ void prep_kernel(const float* __restrict__ W1, const float* __restrict__ b1,
                            const float* __restrict__ g1, const float* __restrict__ be1,
                            const float* __restrict__ m1, const float* __restrict__ v1,
                            const float* __restrict__ W2, const float* __restrict__ b2,
                            const float* __restrict__ g2, const float* __restrict__ be2,
                            const float* __restrict__ m2, const float* __restrict__ v2,
                            float* __restrict__ ws)
{
    int t = blockIdx.x * blockDim.x + threadIdx.x;
    int stride = gridDim.x * blockDim.x;
    for (int q = t; q < HD * ED; q += stride) {       // W1fT [c][j]
        int c = q >> 4, j = q & 15;
        float s = g1[c] / sqrtf(v1[c] + 1e-5f);
        ws[OFF_W1 + q] = W1[j * HD + c] * s;
    }
    for (int c = t; c < HD; c += stride) {            // b1f
        float s = g1[c] / sqrtf(v1[c] + 1e-5f);
        ws[OFF_B1 + c] = b1[c] * s + be1[c] - m1[c] * s;
    }
    for (int k = t; k < KD; k += stride) {            // bf
        float s = g2[k] / sqrtf(v2[k] + 1e-5f);
        ws[OFF_BF + k] = b2[k] * s + be2[k] - m2[k] * s;
    }
    for (int q = t; q < KD * HD; q += stride) {       // W2fT [k][j]
        int k = q >> 5, j = q & 31;
        float s = g2[k] / sqrtf(v2[k] + 1e-5f);
        ws[OFF_W2 + q] = W2[j * KD + k] * s;
    }
}

// ---------------------------------------------------------------------------
// out = x @ root + bias  (also serves as d_out initialization before atomics)
// one thread per (node, o); root reads are L1-resident (4 KB)
// ---------------------------------------------------------------------------
__global__ void root_kernel(const float* __restrict__ x, const float* __restrict__ root,
                            const float* __restrict__ bias, float* __restrict__ out, int nN)
{
    int t = blockIdx.x * blockDim.x + threadIdx.x;
    if (t >= nN * OD) return;
    int o = t & (OD - 1);
    int n = t >> 5;
    const float* xr = x + (size_t)n * HD;
    float acc = bias[o];
#pragma unroll
    for (int i = 0; i < HD; ++i)
        acc = fmaf(xr[i], root[i * OD + o], acc);
    out[t] = acc;
}

// ---------------------------------------------------------------------------
// Fused per-edge kernel: one edge per lane. k-loop indices are wave-uniform
// (blockIdx.y picks the o-chunk) so W2fT/bf reads scalarize to s_loads.
// h[32], msg[OCH] live in registers; the i-loop is a real loop (x_j[i] read
// from global, L1-hit after first touch) to keep code size in I-cache.
// ---------------------------------------------------------------------------
template <bool GUARD>
__global__ __launch_bounds__(64)
void edge_kernel(const float* __restrict__ x, const int* __restrict__ eidx,
                 const float* __restrict__ ea_g, const float* __restrict__ ws,
                 float* __restrict__ out, int nE, int ebase)
{
    int e = ebase + blockIdx.x * 64 + threadIdx.x;
    if (GUARD && e >= nE) return;
    const int obase = blockIdx.y * OCH;   // wave-uniform

    int src = eidx[e];
    int dst = eidx[nE + e];

    const float4* eap = reinterpret_cast<const float4*>(ea_g + (size_t)e * ED);
    float4 a0 = eap[0], a1 = eap[1], a2 = eap[2], a3 = eap[3];
    float ea[ED] = {a0.x, a0.y, a0.z, a0.w, a1.x, a1.y, a1.z, a1.w,
                    a2.x, a2.y, a2.z, a2.w, a3.x, a3.y, a3.z, a3.w};

    const float* w1t = ws + OFF_W1;
    const float* b1f = ws + OFF_B1;
    const float* bf  = ws + OFF_BF;
    const float* w2t = ws + OFF_W2;

    // h = LReLU(ea @ W1f + b1f)
    float h[HD];
#pragma unroll
    for (int c = 0; c < HD; ++c) {
        float acc = b1f[c];
        const float4* r4 = reinterpret_cast<const float4*>(w1t + c * ED);
#pragma unroll
        for (int jq = 0; jq < 4; ++jq) {
            float4 w4 = r4[jq];
            acc = fmaf(ea[jq * 4 + 0], w4.x, acc);
            acc = fmaf(ea[jq * 4 + 1], w4.y, acc);
            acc = fmaf(ea[jq * 4 + 2], w4.z, acc);
            acc = fmaf(ea[jq * 4 + 3], w4.w, acc);
        }
        h[c] = fmaxf(acc, 0.01f * acc);
    }

    float msg[OCH];
#pragma unroll
    for (int o = 0; o < OCH; ++o) msg[o] = 0.f;

    const float* xj = x + (size_t)src * HD;

    for (int i = 0; i < HD; ++i) {        // NOT unrolled: keeps body ~5 KB
        float xv = xj[i];
#pragma unroll
        for (int oo = 0; oo < OCH; ++oo) {
            int k = i * OD + obase + oo;  // wave-uniform
            float acc = bf[k];
            const float4* r4 = reinterpret_cast<const float4*>(w2t + (size_t)k * HD);
#pragma unroll
            for (int jq = 0; jq < 8; ++jq) {
                float4 w4 = r4[jq];
                acc = fmaf(h[jq * 4 + 0], w4.x, acc);
                acc = fmaf(h[jq * 4 + 1], w4.y, acc);
                acc = fmaf(h[jq * 4 + 2], w4.z, acc);
                acc = fmaf(h[jq * 4 + 3], w4.w, acc);
            }
            float w = fmaxf(acc, 0.01f * acc);   // LeakyReLU, slope<1
            msg[oo] = fmaf(xv, w, msg[oo]);
        }
    }

    float* op = out + (size_t)dst * OD + obase;
#pragma unroll
    for (int oo = 0; oo < OCH; ++oo)
        atomicAdd(op + oo, msg[oo]);      // device-scope by default on gfx950
}

// ---------------------------------------------------------------------------
// Fallback (ws too small): same structure, reads raw weights (strided) and
// applies BN fold inline. Correctness path only.
// ---------------------------------------------------------------------------
__global__ __launch_bounds__(64)
void edge_kernel_raw(const float* __restrict__ x, const int* __restrict__ eidx,
                     const float* __restrict__ ea_g,
                     const float* __restrict__ W1, const float* __restrict__ b1,
                     const float* __restrict__ g1, const float* __restrict__ be1,
                     const float* __restrict__ m1, const float* __restrict__ v1,
                     const float* __restrict__ W2, const float* __restrict__ b2,
                     const float* __restrict__ g2, const float* __restrict__ be2,
                     const float* __restrict__ m2, const float* __restrict__ v2,
                     float* __restrict__ out, int nE)
{
    int e = blockIdx.x * 64 + threadIdx.x;
    if (e >= nE) return;
    const int obase = blockIdx.y * OCH;

    int src = eidx[e];
    int dst = eidx[nE + e];

    float ea[ED];
#pragma unroll
    for (int j = 0; j < ED; ++j) ea[j] = ea_g[(size_t)e * ED + j];

    float h[HD];
#pragma unroll
    for (int c = 0; c < HD; ++c) {
        float acc = b1[c];
#pragma unroll
        for (int j = 0; j < ED; ++j) acc = fmaf(ea[j], W1[j * HD + c], acc);
        float s = g1[c] / sqrtf(v1[c] + 1e-5f);
        acc = (acc - m1[c]) * s + be1[c];
        h[c] = fmaxf(acc, 0.01f * acc);
    }

    float msg[OCH];
#pragma unroll
    for (int o = 0; o < OCH; ++o) msg[o] = 0.f;

    const float* xj = x + (size_t)src * HD;
    for (int i = 0; i < HD; ++i) {
        float xv = xj[i];
#pragma unroll
        for (int oo = 0; oo < OCH; ++oo) {
            int k = i * OD + obase + oo;
            float acc = b2[k];
#pragma unroll
            for (int j = 0; j < HD; ++j) acc = fmaf(h[j], W2[j * KD + k], acc);
            float s = g2[k] / sqrtf(v2[k] + 1e-5f);
            acc = (acc - m2[k]) * s + be2[k];
            float w = fmaxf(acc, 0.01f * acc);
            msg[oo] = fmaf(xv, w, msg[oo]);
        }
    }

    float* op = out + (size_t)dst * OD + obase;
#pragma unroll
    for (int oo = 0; oo < OCH; ++oo) atomicAdd(op + oo, msg[oo]);
}

// ---------------------------------------------------------------------------
extern "C" void kernel_launch(void* const* d_in, const int* in_sizes, int n_in,
                              void* d_out, int out_size, void* d_ws, size_t ws_size,
                              hipStream_t stream)
{
    const float* x    = (const float*)d_in[0];
    const int*   eidx = (const int*)  d_in[1];   // harness delivers integer inputs as int32
    const float* ea   = (const float*)d_in[2];
    // d_in[3] = batch (unused)
    const float* W1   = (const float*)d_in[4];
    const float* b1   = (const float*)d_in[5];
    const float* g1   = (const float*)d_in[6];
    const float* be1  = (const float*)d_in[7];
    const float* m1   = (const float*)d_in[8];
    const float* v1   = (const float*)d_in[9];
    const float* W2   = (const float*)d_in[10];
    const float* b2   = (const float*)d_in[11];
    const float* g2   = (const float*)d_in[12];
    const float* be2  = (const float*)d_in[13];
    const float* m2   = (const float*)d_in[14];
    const float* v2   = (const float*)d_in[15];
    const float* root = (const float*)d_in[16];
    const float* bias = (const float*)d_in[17];
    float* out = (float*)d_out;

    int nN = in_sizes[0] / HD;
    int nE = in_sizes[2] / ED;

    // out = x @ root + bias (initializes all of d_out before atomics land)
    root_kernel<<<dim3((nN * OD + 255) / 256), 256, 0, stream>>>(x, root, bias, out, nN);

    bool prepped = ws_size >= (size_t)WS_FLOATS * sizeof(float);
    if (prepped) {
        float* ws = (float*)d_ws;
        prep_kernel<<<128, 256, 0, stream>>>(W1, b1, g1, be1, m1, v1,
                                             W2, b2, g2, be2, m2, v2, ws);
        int full = nE / 64;
        if (full > 0)
            edge_kernel<false><<<dim3(full, OSPLIT), 64, 0, stream>>>(
                x, eidx, ea, ws, out, nE, 0);
        int rem = nE - full * 64;
        if (rem > 0)
            edge_kernel<true><<<dim3(1, OSPLIT), 64, 0, stream>>>(
                x, eidx, ea, ws, out, nE, full * 64);
    } else {
        edge_kernel_raw<<<dim3((nE + 63) / 64, OSPLIT), 64, 0, stream>>>(
            x, eidx, ea, W1, b1, g1, be1, m1, v1,
            W2, b2, g2, be2, m2, v2, out, nE);
    }
}